// Round 3
// baseline (545.872 us; speedup 1.0000x reference)
//
#include <hip/hip_runtime.h>
#include <math.h>

#define B_ 16
#define S_ 1024
#define D_ 512
#define H_ 4
#define INV_TEMP 0.044194173824159216f   // 1/sqrt(512)
#define C_SCALE 0.00390625f              // 2^-8 range guard for fp16 P
 
typedef _Float16 f16;
typedef _Float16 f16x8 __attribute__((ext_vector_type(8)));
typedef _Float16 f16x4 __attribute__((ext_vector_type(4)));
typedef float f32x4 __attribute__((ext_vector_type(4)));

#define AS1(p) ((const __attribute__((address_space(1))) void*)(p))
#define AS3(p) ((__attribute__((address_space(3))) void*)(p))
#define MFMA __builtin_amdgcn_mfma_f32_16x16x32_f16

// ---------------------------------------------------------------------------
// fp32 -> fp16 convert
// ---------------------------------------------------------------------------
__global__ __launch_bounds__(256)
void k_conv(const float* __restrict__ src, f16* __restrict__ dst)
{
    const int i = blockIdx.x * 256 + threadIdx.x;
    const float4 v = ((const float4*)src)[i];
    f16x4 h; h[0] = (f16)v.x; h[1] = (f16)v.y; h[2] = (f16)v.z; h[3] = (f16)v.w;
    ((f16x4*)dst)[i] = h;
}

// ---------------------------------------------------------------------------
// vT[b][e][s] = ELU(x @ W_h^T + b_h)  (stored transposed for PV B-side)
// M = e (A = W tile in LDS), N = s (B = xh streamed from global). Barrier-free
// K-loop. Block 512 thr (8 waves), grid (64 s-blocks, 4 e-blocks) = 256.
// ---------------------------------------------------------------------------
__global__ __launch_bounds__(512, 2)
void k_gemm_v(const f16* __restrict__ xh, const f16* __restrict__ Wh,
              const float* __restrict__ bias, f16* __restrict__ vT)
{
    __shared__ __align__(16) f16 Ws[128 * 520];   // 128 rows, pad to 520
    const int t = threadIdx.x;
    const int wv = t >> 6, lane = t & 63, l15 = lane & 15, quad = lane >> 4;
    const int mh = wv & 1;          // e-half of 64
    const int ns = wv >> 1;         // s-quarter of 64
    const int ebase = blockIdx.y * 128;
    const int sbase = blockIdx.x * 256;

    // stage W tile [128][512] -> LDS [128][520]; one row per wave per iter
#pragma unroll
    for (int i = 0; i < 16; ++i) {
        const int row = i * 8 + wv;
        __builtin_amdgcn_global_load_lds(
            AS1((const char*)(Wh + (size_t)(ebase + row) * D_) + lane * 16),
            AS3((char*)Ws + row * 1040 + lane * 16), 16, 0, 0);
    }
    __syncthreads();

    f32x4 acc[4][4] = {};
#pragma unroll 2
    for (int dc = 0; dc < 16; ++dc) {
        f16x8 af[4], bf[4];
#pragma unroll
        for (int mt = 0; mt < 4; ++mt)
            af[mt] = *(const f16x8*)(Ws + (mh * 64 + mt * 16 + l15) * 520 + dc * 32 + quad * 8);
#pragma unroll
        for (int nt = 0; nt < 4; ++nt)
            bf[nt] = *(const f16x8*)(xh + (size_t)(sbase + ns * 64 + nt * 16 + l15) * D_ + dc * 32 + quad * 8);
#pragma unroll
        for (int mt = 0; mt < 4; ++mt)
#pragma unroll
            for (int nt = 0; nt < 4; ++nt)
                acc[mt][nt] = MFMA(af[mt], bf[nt], acc[mt][nt], 0, 0, 0);
    }

#pragma unroll
    for (int mt = 0; mt < 4; ++mt) {
#pragma unroll
        for (int r = 0; r < 4; ++r) {
            const int e = ebase + mh * 64 + mt * 16 + quad * 4 + r;
            const float be = bias[e];
#pragma unroll
            for (int nt = 0; nt < 4; ++nt) {
                const int sg = sbase + ns * 64 + nt * 16 + l15;
                float z = acc[mt][nt][r] + be;
                z = (z > 0.0f) ? z : (expf(z) - 1.0f);
                const int b = sg >> 10, s = sg & 1023;
                vT[((size_t)b * D_ + e) * S_ + s] = (f16)z;
            }
        }
    }
}

// ---------------------------------------------------------------------------
// Fused: scores (masked, fp32) -> ss accumulation -> fp16 P chunk in LDS ->
// PV accumulate -> final 1/max(norm,eps) scale. No score tensor in HBM.
// Block 512 thr (8 waves) handles q-tile 64 for one batch.
// grid (16 q-tiles, 16 batches) = 256 blocks.
// ---------------------------------------------------------------------------
__global__ __launch_bounds__(512, 2)
void k_fused(const f16* __restrict__ xh, const f16* __restrict__ vT,
             const int* __restrict__ etype, f16* __restrict__ xnext,
             float* __restrict__ out, const int accum)
{
    __shared__ __align__(16) f16 xq[64 * 520];     // 66560 B  (q rows, padded)
    __shared__ __align__(16) f16 Sc[64 * 264];     // 33792 B  (P chunk, padded)
    __shared__ float ssw[8][64];
    __shared__ float invq[64];
    __shared__ unsigned char padk[1024];

    const int t = threadIdx.x;
    const int wv = t >> 6, lane = t & 63, l15 = lane & 15, quad = lane >> 4;
    const int b = blockIdx.y;
    const int bq = blockIdx.x * 64;
    const f16* xb  = xh + (size_t)b * S_ * D_;
    const f16* vTb = vT + (size_t)b * D_ * S_;

    // stage x_q tile [64][512] -> LDS [64][520]; one row per wave per iter
#pragma unroll
    for (int i = 0; i < 8; ++i) {
        const int row = i * 8 + wv;
        __builtin_amdgcn_global_load_lds(
            AS1((const char*)(xb + (size_t)(bq + row) * D_) + lane * 16),
            AS3((char*)xq + row * 1040 + lane * 16), 16, 0, 0);
    }
    if (t < 256) {
        const int4 et = *(const int4*)(etype + b * S_ + t * 4);
        padk[t * 4 + 0] = (et.x == 0);
        padk[t * 4 + 1] = (et.y == 0);
        padk[t * 4 + 2] = (et.z == 0);
        padk[t * 4 + 3] = (et.w == 0);
    }
    __syncthreads();

    f32x4 oacc[4][4] = {};        // O[q=64][e-slice 64] per wave
    float ss_loc[4][4] = {};      // per-lane partial sum-of-squares per q row
    const int eb = wv * 64;       // this wave's e-range in phase 2

    for (int kc = 0; kc < 4; ++kc) {
        // ---- phase 1: this wave computes Sc[:, wv*32 .. wv*32+32) ----
        const int kb = kc * 256 + wv * 32;
        f32x4 sacc[4][2] = {};
#pragma unroll 2
        for (int dc = 0; dc < 16; ++dc) {
            f16x8 af[4], bf[2];
#pragma unroll
            for (int mt = 0; mt < 4; ++mt)
                af[mt] = *(const f16x8*)(xq + (mt * 16 + l15) * 520 + dc * 32 + quad * 8);
#pragma unroll
            for (int nt = 0; nt < 2; ++nt)
                bf[nt] = *(const f16x8*)(xb + (size_t)(kb + nt * 16 + l15) * D_ + dc * 32 + quad * 8);
#pragma unroll
            for (int mt = 0; mt < 4; ++mt)
#pragma unroll
                for (int nt = 0; nt < 2; ++nt)
                    sacc[mt][nt] = MFMA(af[mt], bf[nt], sacc[mt][nt], 0, 0, 0);
        }
        // mask + ss + fp16 chunk write
#pragma unroll
        for (int nt = 0; nt < 2; ++nt) {
            const int kcol = kb + nt * 16 + l15;
            const bool pad = padk[kcol] != 0;
#pragma unroll
            for (int mt = 0; mt < 4; ++mt) {
#pragma unroll
                for (int r = 0; r < 4; ++r) {
                    const int q = bq + mt * 16 + quad * 4 + r;
                    float sv = sacc[mt][nt][r] * INV_TEMP;
                    sv = ((kcol > q) || pad) ? sv : 0.0f;
                    ss_loc[mt][r] += sv * sv;
                    Sc[(mt * 16 + quad * 4 + r) * 264 + wv * 32 + nt * 16 + l15] =
                        (f16)(sv * C_SCALE);
                }
            }
        }
        __syncthreads();
        // ---- phase 2: PV accumulate on this kv-chunk; wave owns e-range ----
#pragma unroll 2
        for (int kk = 0; kk < 8; ++kk) {
            f16x8 af[4], bf[4];
#pragma unroll
            for (int mt = 0; mt < 4; ++mt)
                af[mt] = *(const f16x8*)(Sc + (mt * 16 + l15) * 264 + kk * 32 + quad * 8);
#pragma unroll
            for (int nt = 0; nt < 4; ++nt)
                bf[nt] = *(const f16x8*)(vTb + (size_t)(eb + nt * 16 + l15) * S_ +
                                         kc * 256 + kk * 32 + quad * 8);
#pragma unroll
            for (int mt = 0; mt < 4; ++mt)
#pragma unroll
                for (int nt = 0; nt < 4; ++nt)
                    oacc[mt][nt] = MFMA(af[mt], bf[nt], oacc[mt][nt], 0, 0, 0);
        }
        __syncthreads();
    }

    // ---- row-norm reduction: sum ss over 16 lanes, then over 8 waves ----
#pragma unroll
    for (int mt = 0; mt < 4; ++mt)
#pragma unroll
        for (int r = 0; r < 4; ++r) {
            float v = ss_loc[mt][r];
            v += __shfl_xor(v, 1); v += __shfl_xor(v, 2);
            v += __shfl_xor(v, 4); v += __shfl_xor(v, 8);
            if (l15 == 0) ssw[wv][mt * 16 + quad * 4 + r] = v;
        }
    __syncthreads();
    if (t < 64) {
        float s = 0.0f;
#pragma unroll
        for (int w = 0; w < 8; ++w) s += ssw[w][t];
        invq[t] = 1.0f / (C_SCALE * fmaxf(sqrtf(s), 1e-5f));
    }
    __syncthreads();

    // ---- epilogue: scale, accumulate into out, write xnext ----
#pragma unroll
    for (int mt = 0; mt < 4; ++mt) {
#pragma unroll
        for (int r = 0; r < 4; ++r) {
            const int q = mt * 16 + quad * 4 + r;
            const float inv = invq[q];
            const size_t rowo = ((size_t)b * S_ + bq + q) * D_;
#pragma unroll
            for (int nt = 0; nt < 4; ++nt) {
                const int e = eb + nt * 16 + l15;
                const float val = oacc[mt][nt][r] * inv;
                const size_t o = rowo + e;
                out[o] = accum ? (out[o] + val) : val;
                xnext[o] = (f16)val;
            }
        }
    }
}

// ---------------------------------------------------------------------------
// Workspace: X0 @0 (16M), X1 @16M (16M), vT @32M (16M), Wh @48M (2M)
// ---------------------------------------------------------------------------
extern "C" void kernel_launch(void* const* d_in, const int* in_sizes, int n_in,
                              void* d_out, int out_size, void* d_ws, size_t ws_size,
                              hipStream_t stream) {
    const float* x0    = (const float*)d_in[0];
    const int*   etype = (const int*)d_in[2];
    const float* W     = (const float*)d_in[3];
    const float* bias  = (const float*)d_in[4];
    float* out = (float*)d_out;

    char* ws = (char*)d_ws;
    f16* X0 = (f16*)(ws);
    f16* X1 = (f16*)(ws + (16u << 20));
    f16* vT = (f16*)(ws + (32u << 20));
    f16* Wh = (f16*)(ws + (48u << 20));

    k_conv<<<8192, 256, 0, stream>>>(x0, X0);
    k_conv<<<1024, 256, 0, stream>>>(W, Wh);

    const dim3 gridV(64, 4);
    const dim3 gridF(16, 16);
    for (int h = 0; h < H_; ++h) {
        f16* Xc = (h & 1) ? X1 : X0;
        f16* Xn = (h & 1) ? X0 : X1;
        k_gemm_v<<<gridV, 512, 0, stream>>>(Xc, Wh + (size_t)h * D_ * D_,
                                            bias + (size_t)h * D_, vT);
        k_fused <<<gridF, 512, 0, stream>>>(Xc, vT, etype, Xn, out, h > 0);
    }
}